// Round 14
// baseline (87.016 us; speedup 1.0000x reference)
//
#include <hip/hip_runtime.h>
#include <math.h>

// Problem constants
#define BATCH 2
#define SEQ   2048
#define DIM   1024
#define RANK  256
#define HEADS 16
#define HS    16
#define DH    64
#define MROWS 4096

#define QSCALE 0.36067376f   // 0.25 * log2(e), folded into normalized q

typedef __attribute__((ext_vector_type(8)))  short    short8;   // 8 bf16
typedef __attribute__((ext_vector_type(4)))  float    f32x4;
typedef __attribute__((ext_vector_type(16))) float    f32x16;
typedef __attribute__((ext_vector_type(2)))  unsigned uint2v;

#define GPTR const __attribute__((address_space(1))) unsigned int*
#define LPTR __attribute__((address_space(3))) unsigned int*

__device__ __forceinline__ unsigned short f2bf(float f) {
    union { float f; unsigned u; } v; v.f = f;
    return (unsigned short)((v.u + 0x7FFFu + ((v.u >> 16) & 1u)) >> 16);  // RNE
}
__device__ __forceinline__ float bf2f(unsigned short h) {
    union { unsigned u; float f; } v; v.u = ((unsigned)h) << 16;
    return v.f;
}

// ---------------- FUSED MFMA GEMM: f32 in (x, Wqk, Wv), bf16 MFMA, conv3 deleted ----------------
// 128x64 tile, BK=64. Reg-staged f32 -> cvt_pk -> XOR-swizzled bf16 LDS (write-side
// swizzle; rule-21 both-sides). One raw barrier/tile with lgkmcnt(0) ONLY -- next
// tile's 12 f32 loads stay in flight across it (T14 async split). 48KB LDS dbuf.
__global__ __launch_bounds__(256, 3) void gemm_fused(const float* __restrict__ A,
                                                     const float* __restrict__ Wqk,
                                                     const float* __restrict__ Wv,
                                                     unsigned short* __restrict__ qkb,
                                                     unsigned short* __restrict__ vt)
{
    __shared__ __align__(16) unsigned short Alds[2][128 * 64];  // 32 KB
    __shared__ __align__(16) unsigned short Blds[2][64 * 64];   // 16 KB

    const int tid = threadIdx.x;
    const int w = tid >> 6, lane = tid & 63;
    const int lr = lane & 15, lg = lane >> 4;
    const int wm = w >> 1, wn = w & 1;

    const int Lf = blockIdx.x;                 // 768 blocks
    const int wg = (Lf & 7) * 96 + (Lf >> 3);  // bijective XCD chunking
    const int bm = (wg & 31) * 128;
    const int bn = (wg >> 5) * 64;

    // concat W rows: 0..511 -> Wqk, 512..1535 -> Wv (each 64-row tile is uniform)
    const float* Wsrc = (bn < 512) ? (Wqk + (size_t)bn * 1024)
                                   : (Wv + (size_t)(bn - 512) * 1024);

    const int rsub = tid >> 4;        // 0..15 (row-within-16 group)
    const int kq   = tid & 15;        // f32-quad: k = 4*kq (coalesced 4KB wave-loads)

    float4 avreg[8], bvreg[4];

#define LOADF(kt_) do { const int k0_ = (kt_) * 64;                                               \
        _Pragma("unroll") for (int jj = 0; jj < 8; ++jj)                                          \
            avreg[jj] = *(const float4*)&A[(size_t)(bm + jj * 16 + rsub) * 1024 + k0_ + 4 * kq];  \
        _Pragma("unroll") for (int jj = 0; jj < 4; ++jj)                                          \
            bvreg[jj] = *(const float4*)&Wsrc[(size_t)(jj * 16 + rsub) * 1024 + k0_ + 4 * kq];    \
    } while (0)

    // write-side swizzle: byte = r*128 + 16*((kq>>1) ^ (r&7)) + 8*(kq&1)  (matches read)
#define CVTWR(buf_) do {                                                                          \
        _Pragma("unroll") for (int jj = 0; jj < 8; ++jj) {                                        \
            const int r = jj * 16 + rsub;                                                         \
            unsigned u0, u1;                                                                      \
            asm("v_cvt_pk_bf16_f32 %0, %1, %2" : "=v"(u0) : "v"(avreg[jj].x), "v"(avreg[jj].y));  \
            asm("v_cvt_pk_bf16_f32 %0, %1, %2" : "=v"(u1) : "v"(avreg[jj].z), "v"(avreg[jj].w));  \
            uint2 pkv; pkv.x = u0; pkv.y = u1;                                                    \
            *(uint2*)((char*)&Alds[buf_][0] + r * 128 + 16 * ((kq >> 1) ^ (r & 7)) + 8 * (kq & 1)) = pkv; \
        }                                                                                         \
        _Pragma("unroll") for (int jj = 0; jj < 4; ++jj) {                                        \
            const int r = jj * 16 + rsub;                                                         \
            unsigned u0, u1;                                                                      \
            asm("v_cvt_pk_bf16_f32 %0, %1, %2" : "=v"(u0) : "v"(bvreg[jj].x), "v"(bvreg[jj].y));  \
            asm("v_cvt_pk_bf16_f32 %0, %1, %2" : "=v"(u1) : "v"(bvreg[jj].z), "v"(bvreg[jj].w));  \
            uint2 pkv; pkv.x = u0; pkv.y = u1;                                                    \
            *(uint2*)((char*)&Blds[buf_][0] + r * 128 + 16 * ((kq >> 1) ^ (r & 7)) + 8 * (kq & 1)) = pkv; \
        }                                                                                         \
    } while (0)

    f32x4 acc[4][2] = {};

    LOADF(0);
    CVTWR(0);          // compiler auto-waitcnts vmcnt before first cvt use

    #pragma unroll 1
    for (int kt = 0; kt < 16; ++kt) {
        if (kt + 1 < 16) LOADF(kt + 1);                    // f32 prefetch (rides across barrier)
        asm volatile("s_waitcnt lgkmcnt(0)" ::: "memory"); // ds_writes visible; NO vmcnt drain
        __builtin_amdgcn_s_barrier();                      // buf[kt&1] ready for all waves

        const int buf = kt & 1;
        #pragma unroll
        for (int kk = 0; kk < 2; ++kk) {
            short8 af[4], bfr[2];
            #pragma unroll
            for (int mi = 0; mi < 4; ++mi) {
                const int row = wm * 64 + mi * 16 + lr;
                af[mi] = *(const short8*)&Alds[buf][row * 64 + 8 * ((kk * 4 + lg) ^ (row & 7))];
            }
            #pragma unroll
            for (int ni = 0; ni < 2; ++ni) {
                const int row = wn * 32 + ni * 16 + lr;
                bfr[ni] = *(const short8*)&Blds[buf][row * 64 + 8 * ((kk * 4 + lg) ^ (row & 7))];
            }
            #pragma unroll
            for (int mi = 0; mi < 4; ++mi)
                #pragma unroll
                for (int ni = 0; ni < 2; ++ni)
                    acc[mi][ni] = __builtin_amdgcn_mfma_f32_16x16x32_bf16(af[mi], bfr[ni], acc[mi][ni], 0, 0, 0);
        }

        if (kt + 1 < 16) CVTWR((kt + 1) & 1);   // loads landed under compute; write other buf
    }
#undef LOADF
#undef CVTWR

    if (bn < 512) {
        #pragma unroll
        for (int mi = 0; mi < 4; ++mi) {
            const int rbase = bm + wm * 64 + mi * 16 + lg * 4;
            #pragma unroll
            for (int ni = 0; ni < 2; ++ni) {
                const int col = bn + wn * 32 + ni * 16 + lr;
                #pragma unroll
                for (int r = 0; r < 4; ++r)
                    qkb[(size_t)(rbase + r) * 512 + col] = f2bf(acc[mi][ni][r]);
            }
        }
    } else {
        const int nb = bn - 512;
        #pragma unroll
        for (int mi = 0; mi < 4; ++mi) {
            const int m = bm + wm * 64 + mi * 16 + lg * 4;
            const int bb = m >> 11, ms = m & 2047;
            #pragma unroll
            for (int ni = 0; ni < 2; ++ni) {
                const int d = nb + wn * 32 + ni * 16 + lr;
                ushort4 pk;
                pk.x = f2bf(acc[mi][ni][0]); pk.y = f2bf(acc[mi][ni][1]);
                pk.z = f2bf(acc[mi][ni][2]); pk.w = f2bf(acc[mi][ni][3]);
                *(ushort4*)&vt[((size_t)bb * DIM + d) * SEQ + ms] = pk;
            }
        }
    }
}

// ---------------- L2 normalize; outputs HEAD-MAJOR qn/kn [bh][n][16] ----------------
__global__ __launch_bounds__(256) void l2norm_split(const unsigned short* __restrict__ qkb,
                                                    unsigned short* __restrict__ qn,
                                                    unsigned short* __restrict__ kn)
{
    const int row = blockIdx.x;
    const int t = threadIdx.x;
    const unsigned short* p = qkb + (size_t)row * 512;
    float q = bf2f(p[t]);
    float k = bf2f(p[t + 256]);
    float sq = q * q, sk = k * k;
    #pragma unroll
    for (int off = 32; off > 0; off >>= 1) {
        sq += __shfl_down(sq, off);
        sk += __shfl_down(sk, off);
    }
    __shared__ float sh[8];
    const int wid = t >> 6;
    if ((t & 63) == 0) { sh[wid * 2] = sq; sh[wid * 2 + 1] = sk; }
    __syncthreads();
    sq = sh[0] + sh[2] + sh[4] + sh[6];
    sk = sh[1] + sh[3] + sh[5] + sh[7];
    const float rq = QSCALE / fmaxf(sqrtf(sq), 1e-6f);
    const float rk = 1.0f   / fmaxf(sqrtf(sk), 1e-6f);

    const int b = row >> 11, n = row & 2047;
    const int head = t >> 4, hs = t & 15;
    const size_t o = (((size_t)b * HEADS + head) * SEQ + n) * 16 + hs;
    qn[o] = f2bf(q * rq);
    kn[o] = f2bf(k * rk);
}

// ---------------- attn: 8-wave blocks, wave = (seg, qh, kh)  [R12, best measured] ----------------
template<bool MASK>
__device__ __forceinline__ void segpv(const short8 ak0, const short8 ak1, const short8 bq,
                                      const unsigned short* Vs, int kb, int kh, int hi,
                                      int l31, int qg, f32x16 o[2], float& lp)
{
    const f32x16 z = {};
    short8 pa[4];

    const f32x16 s0 = __builtin_amdgcn_mfma_f32_32x32x16_bf16(ak0, bq, z, 0, 0, 0);
    {
        float p0[16];
        #pragma unroll
        for (int r = 0; r < 16; ++r) {
            float e = __builtin_exp2f(s0[r]);
            if (MASK) {
                const int kl = kb + (r & 3) + 8 * (r >> 2) + 4 * hi;
                e = (kl > qg) ? 0.0f : e;
            }
            p0[r] = e; lp += e;
        }
        #pragma unroll
        for (int g = 0; g < 2; ++g) {
            const int jj = 2 * g;
            unsigned a0, a1, b0, b1;
            asm("v_cvt_pk_bf16_f32 %0, %1, %2" : "=v"(a0) : "v"(p0[4*jj]),     "v"(p0[4*jj + 1]));
            asm("v_cvt_pk_bf16_f32 %0, %1, %2" : "=v"(b0) : "v"(p0[4*jj + 2]), "v"(p0[4*jj + 3]));
            asm("v_cvt_pk_bf16_f32 %0, %1, %2" : "=v"(a1) : "v"(p0[4*jj + 4]), "v"(p0[4*jj + 5]));
            asm("v_cvt_pk_bf16_f32 %0, %1, %2" : "=v"(b1) : "v"(p0[4*jj + 6]), "v"(p0[4*jj + 7]));
            const uint2v r0 = __builtin_amdgcn_permlane32_swap(a0, a1, false, false);
            const uint2v r1 = __builtin_amdgcn_permlane32_swap(b0, b1, false, false);
            union { short8 s; unsigned u[4]; } pu;
            pu.u[0] = r0[0]; pu.u[1] = r1[0]; pu.u[2] = r0[1]; pu.u[3] = r1[1];
            pa[g] = pu.s;
        }
    }
    const f32x16 s1 = __builtin_amdgcn_mfma_f32_32x32x16_bf16(ak1, bq, z, 0, 0, 0);
    {
        float p1[16];
        #pragma unroll
        for (int r = 0; r < 16; ++r) {
            float e = __builtin_exp2f(s1[r]);
            if (MASK) {
                const int kl = kb + 32 + (r & 3) + 8 * (r >> 2) + 4 * hi;
                e = (kl > qg) ? 0.0f : e;
            }
            p1[r] = e; lp += e;
        }
        #pragma unroll
        for (int g = 0; g < 2; ++g) {
            const int jj = 2 * g;
            unsigned a0, a1, b0, b1;
            asm("v_cvt_pk_bf16_f32 %0, %1, %2" : "=v"(a0) : "v"(p1[4*jj]),     "v"(p1[4*jj + 1]));
            asm("v_cvt_pk_bf16_f32 %0, %1, %2" : "=v"(b0) : "v"(p1[4*jj + 2]), "v"(p1[4*jj + 3]));
            asm("v_cvt_pk_bf16_f32 %0, %1, %2" : "=v"(a1) : "v"(p1[4*jj + 4]), "v"(p1[4*jj + 5]));
            asm("v_cvt_pk_bf16_f32 %0, %1, %2" : "=v"(b1) : "v"(p1[4*jj + 6]), "v"(p1[4*jj + 7]));
            const uint2v r0 = __builtin_amdgcn_permlane32_swap(a0, a1, false, false);
            const uint2v r1 = __builtin_amdgcn_permlane32_swap(b0, b1, false, false);
            union { short8 s; unsigned u[4]; } pu;
            pu.u[0] = r0[0]; pu.u[1] = r1[0]; pu.u[2] = r0[1]; pu.u[3] = r1[1];
            pa[2 + g] = pu.s;
        }
    }

    #pragma unroll
    for (int g = 0; g < 4; ++g)
        #pragma unroll
        for (int half = 0; half < 2; ++half) {
            const int row = half * 32 + l31;
            const int slot = (8 * kh + 2 * g + hi) ^ (row & 15);
            const short8 bv = *(const short8*)&Vs[row * 128 + 8 * slot];
            o[half] = __builtin_amdgcn_mfma_f32_32x32x16_bf16(pa[g], bv, o[half], 0, 0, 0);
        }
}

__global__ __launch_bounds__(512, 4) void attn_w8(const unsigned short* __restrict__ qn,
                                                  const unsigned short* __restrict__ kn,
                                                  const unsigned short* __restrict__ vt,
                                                  float* __restrict__ out)
{
    const int L = blockIdx.x;            // 512; L%8 == bh%8 -> XCD-pinned
    const int bh = L & 31;
    const int p  = L >> 5;               // pair {31-p, p}
    const int h = bh & 15, b = bh >> 4;

    const int tid = threadIdx.x, w = tid >> 6, lane = tid & 63;
    const int seg = w >> 2, qh = (w >> 1) & 1, kh = w & 1;
    const int l31 = lane & 31, hi = lane >> 5;

    const int qt  = seg ? p : 31 - p;
    const int nts = (qt >> 1) + 1;       // this wave's active tiles
    const int nt0 = ((31 - p) >> 1) + 1; // loop trip count (heavy)
    const int band = qt * 64 + qh * 32;
    const int qg = band + l31;

    __shared__ __align__(16) unsigned char smem[33792];

    const unsigned short* qbh = qn + (size_t)bh * SEQ * 16;
    const unsigned short* kbh = kn + (size_t)bh * SEQ * 16;

    const short8 bq = *(const short8*)&qbh[qg * 16 + 8 * hi];

    f32x16 o[2] = {};
    float lp = 0.0f;

    const unsigned short* kwin = kbh + (64 * kh + l31) * 16 + 8 * hi;
    short8 ak0 = *(const short8*)(kwin);
    short8 ak1 = *(const short8*)(kwin + 32 * 16);

    const int vsub = lane >> 4, vslot = lane & 15;

#define STAGEV(kt_, buf_) do {                                                                    \
        const int k0_ = (kt_) * 128;                                                              \
        _Pragma("unroll")                                                                         \
        for (int i = 0; i < 2; ++i) {                                                             \
            const int c = 2 * w + i;                                                              \
            const int dh = 4 * c + vsub;                                                          \
            const int so = 8 * (vslot ^ (dh & 15));                                               \
            __builtin_amdgcn_global_load_lds(                                                     \
                (GPTR)&vt[((size_t)b * DIM + h * DH + dh) * SEQ + k0_ + so],                      \
                (LPTR)(smem + (buf_) * 16384 + c * 1024), 16, 0, 0);                              \
        }                                                                                         \
    } while (0)

    STAGEV(0, 0);

    #pragma unroll 1
    for (int kt = 0; kt < nt0; ++kt) {
        short8 an0 = ak0, an1 = ak1;
        if (kt + 1 < nt0) {
            STAGEV(kt + 1, (kt + 1) & 1);
            an0 = *(const short8*)(kwin + (size_t)(kt + 1) * 128 * 16);
            an1 = *(const short8*)(kwin + (size_t)(kt + 1) * 128 * 16 + 32 * 16);
            asm volatile("s_waitcnt vmcnt(4)" ::: "memory");   // drain tile kt only
        } else {
            asm volatile("s_waitcnt vmcnt(0)" ::: "memory");
        }
        __builtin_amdgcn_sched_barrier(0);
        __builtin_amdgcn_s_barrier();        // stage(kt) visible to all waves

        if (kt < nts) {
            const unsigned short* Vs = (const unsigned short*)(smem + (kt & 1) * 16384);
            const int kb = kt * 128 + 64 * kh;
            __builtin_amdgcn_s_setprio(1);
            if (kt < nts - 1) {
                segpv<false>(ak0, ak1, bq, Vs, kb, kh, hi, l31, qg, o, lp);
            } else if (kb <= band + 31) {
                if (kb + 63 <= band) segpv<false>(ak0, ak1, bq, Vs, kb, kh, hi, l31, qg, o, lp);
                else                 segpv<true >(ak0, ak1, bq, Vs, kb, kh, hi, l31, qg, o, lp);
            }
            __builtin_amdgcn_s_setprio(0);
        }

        ak0 = an0; ak1 = an1;
        __builtin_amdgcn_s_barrier();        // all waves done reading buf kt
    }
#undef STAGEV

    // ---- epilogue: per-seg 2-way kh merge, normalize, store ----
    lp += __shfl_xor(lp, 32);

    __syncthreads();
    float* Os = (float*)(smem + seg * 16384);
    float* Ls = (float*)(smem + 32768 + seg * 512);

    if (kh == 1) {
        #pragma unroll
        for (int half = 0; half < 2; ++half)
            #pragma unroll
            for (int r = 0; r < 16; ++r) {
                const int q = (r & 3) + 8 * (r >> 2) + 4 * hi;
                Os[(qh * 32 + q) * 64 + half * 32 + l31] = o[half][r];
            }
        Ls[qh * 64 + lane] = lp;
    }
    __syncthreads();
    if (kh == 0) {
        const float lt = lp + Ls[qh * 64 + lane];
        const float inv = 1.0f / fmaxf(lt, 1e-6f);
        #pragma unroll
        for (int r = 0; r < 16; ++r) {
            const int q = (r & 3) + 8 * (r >> 2) + 4 * hi;
            const float iv = __shfl(inv, q);
            #pragma unroll
            for (int half = 0; half < 2; ++half) {
                const float v = (o[half][r] + Os[(qh * 32 + q) * 64 + half * 32 + l31]) * iv;
                __builtin_nontemporal_store(v,
                    &out[((size_t)b * SEQ + band + q) * DIM + h * DH + half * 32 + l31]);
            }
        }
    }
}

extern "C" void kernel_launch(void* const* d_in, const int* in_sizes, int n_in,
                              void* d_out, int out_size, void* d_ws, size_t ws_size,
                              hipStream_t stream)
{
    const float* x   = (const float*)d_in[0];
    // d_in[1] = mask (causal, analytic)
    const float* Wqk = (const float*)d_in[2];
    const float* Wv  = (const float*)d_in[3];
    float* out = (float*)d_out;

    // workspace (16 MB): qkb 4MB | vt 8MB | qn 2MB | kn 2MB  (xb/wcat deleted)
    unsigned short* qkb = (unsigned short*)d_ws;
    unsigned short* vt  = qkb + (size_t)MROWS * 512;
    unsigned short* qn  = vt  + (size_t)BATCH * DIM * SEQ;   // [32 bh][2048][16]
    unsigned short* kn  = qn  + (size_t)32 * SEQ * 16;

    gemm_fused<<<768, 256, 0, stream>>>(x, Wqk, Wv, qkb, vt);
    l2norm_split<<<MROWS, 256, 0, stream>>>(qkb, qn, kn);
    attn_w8<<<512, 512, 0, stream>>>(qn, kn, vt, out);
}

// Round 15
// 67.373 us; speedup vs baseline: 1.2916x; 1.2916x over previous
//
#include <hip/hip_runtime.h>
#include <math.h>

// Problem constants
#define BATCH 2
#define SEQ   2048
#define DIM   1024
#define RANK  256
#define HEADS 16
#define HS    16
#define DH    64
#define MROWS 4096

#define QSCALE 0.36067376f   // 0.25 * log2(e), folded into normalized q

typedef __attribute__((ext_vector_type(8)))  short    short8;   // 8 bf16
typedef __attribute__((ext_vector_type(4)))  float    f32x4;
typedef __attribute__((ext_vector_type(16))) float    f32x16;
typedef __attribute__((ext_vector_type(2)))  unsigned uint2v;

#define GPTR const __attribute__((address_space(1))) unsigned int*
#define LPTR __attribute__((address_space(3))) unsigned int*

__device__ __forceinline__ unsigned short f2bf(float f) {
    union { float f; unsigned u; } v; v.f = f;
    return (unsigned short)((v.u + 0x7FFFu + ((v.u >> 16) & 1u)) >> 16);  // RNE
}
__device__ __forceinline__ float bf2f(unsigned short h) {
    union { unsigned u; float f; } v; v.u = ((unsigned)h) << 16;
    return v.f;
}

// ---------------- fused f32 -> bf16 convert for x, Wqk, Wv ----------------
#define XQ   1048576
#define WQKQ 131072
#define WVQ  262144
__global__ __launch_bounds__(256) void conv3(const float* __restrict__ x,
                                             const float* __restrict__ wqk,
                                             const float* __restrict__ wv,
                                             unsigned short* __restrict__ xb,
                                             unsigned short* __restrict__ wcat)
{
    const int i = blockIdx.x * 256 + threadIdx.x;
    const float* src; unsigned short* dst; int j;
    if (i < XQ)              { src = x;   dst = xb;   j = i; }
    else if (i < XQ + WQKQ)  { src = wqk; dst = wcat; j = i - XQ; }
    else                     { src = wv;  dst = wcat + (size_t)4 * WQKQ; j = i - XQ - WQKQ; }
    float4 v = ((const float4*)src)[j];
    ushort4 o; o.x = f2bf(v.x); o.y = f2bf(v.y); o.z = f2bf(v.z); o.w = f2bf(v.w);
    ((ushort4*)dst)[j] = o;
}

// ---------------- MFMA GEMM: 128x64, BK=64, DBUF + counted vmcnt ----------------
// XCD-LOCAL OPERAND REUSE: XCD x owns m-tiles [4x,4x+4) x ALL n-tiles.
// Per-XCD working set = 1MB A + 3.1MB W = 4.1MB ~ one L2; all 96 blocks/XCD
// co-resident (3/CU) -> A rows fetched once chip-wide, W once per XCD.
__global__ __launch_bounds__(256, 3) void gemm_mfma(const unsigned short* __restrict__ A,
                                                    const unsigned short* __restrict__ W,
                                                    unsigned short* __restrict__ qkb,
                                                    unsigned short* __restrict__ vt)
{
    __shared__ __align__(16) unsigned short Alds[2][128 * 64];  // 32 KB
    __shared__ __align__(16) unsigned short Blds[2][64 * 64];   // 16 KB

    const int tid = threadIdx.x;
    const int w = tid >> 6, lane = tid & 63;
    const int lr = lane & 15, lg = lane >> 4;
    const int wm = w >> 1, wn = w & 1;

    const int Lf = blockIdx.x;                 // 768 blocks
    const int xcd = Lf & 7;
    const int i5 = Lf >> 3;                    // 0..95 within XCD
    const int bm = (4 * xcd + (i5 & 3)) * 128; // m-tiles 4x..4x+3
    const int bn = (i5 >> 2) * 64;             // all 24 n-tiles

    const int rs = lane >> 3, cs = lane & 7;

    f32x4 acc[4][2] = {};

#define STAGEG(kt_, buf_) do {                                                        \
        const int k0_ = (kt_) * 64;                                                   \
        _Pragma("unroll")                                                             \
        for (int i = 0; i < 4; ++i) {                                                 \
            const int r = w * 32 + i * 8 + rs;                                        \
            __builtin_amdgcn_global_load_lds(                                         \
                (GPTR)&A[(size_t)(bm + r) * 1024 + k0_ + 8 * (cs ^ (r & 7))],         \
                (LPTR)&Alds[buf_][(w * 32 + i * 8) * 64], 16, 0, 0);                  \
        }                                                                             \
        _Pragma("unroll")                                                             \
        for (int i = 0; i < 2; ++i) {                                                 \
            const int r = w * 16 + i * 8 + rs;                                        \
            __builtin_amdgcn_global_load_lds(                                         \
                (GPTR)&W[(size_t)(bn + r) * 1024 + k0_ + 8 * (cs ^ (r & 7))],         \
                (LPTR)&Blds[buf_][(w * 16 + i * 8) * 64], 16, 0, 0);                  \
        }                                                                             \
    } while (0)

    STAGEG(0, 0);

    #pragma unroll 1
    for (int kt = 0; kt < 16; ++kt) {
        if (kt + 1 < 16) {
            STAGEG(kt + 1, (kt + 1) & 1);
            asm volatile("s_waitcnt vmcnt(6)" ::: "memory");   // drain tile kt only
        } else {
            asm volatile("s_waitcnt vmcnt(0)" ::: "memory");
        }
        __builtin_amdgcn_sched_barrier(0);
        __builtin_amdgcn_s_barrier();

        const int buf = kt & 1;
        #pragma unroll
        for (int kk = 0; kk < 2; ++kk) {
            short8 af[4], bfr[2];
            #pragma unroll
            for (int mi = 0; mi < 4; ++mi) {
                const int row = wm * 64 + mi * 16 + lr;
                af[mi] = *(const short8*)&Alds[buf][row * 64 + 8 * ((kk * 4 + lg) ^ (row & 7))];
            }
            #pragma unroll
            for (int ni = 0; ni < 2; ++ni) {
                const int row = wn * 32 + ni * 16 + lr;
                bfr[ni] = *(const short8*)&Blds[buf][row * 64 + 8 * ((kk * 4 + lg) ^ (row & 7))];
            }
            #pragma unroll
            for (int mi = 0; mi < 4; ++mi)
                #pragma unroll
                for (int ni = 0; ni < 2; ++ni)
                    acc[mi][ni] = __builtin_amdgcn_mfma_f32_16x16x32_bf16(af[mi], bfr[ni], acc[mi][ni], 0, 0, 0);
        }
        __builtin_amdgcn_s_barrier();   // all waves done with buf before restage
    }
#undef STAGEG

    if (bn < 512) {
        #pragma unroll
        for (int mi = 0; mi < 4; ++mi) {
            const int rbase = bm + wm * 64 + mi * 16 + lg * 4;
            #pragma unroll
            for (int ni = 0; ni < 2; ++ni) {
                const int col = bn + wn * 32 + ni * 16 + lr;
                #pragma unroll
                for (int r = 0; r < 4; ++r)
                    qkb[(size_t)(rbase + r) * 512 + col] = f2bf(acc[mi][ni][r]);
            }
        }
    } else {
        const int nb = bn - 512;
        #pragma unroll
        for (int mi = 0; mi < 4; ++mi) {
            const int m = bm + wm * 64 + mi * 16 + lg * 4;
            const int bb = m >> 11, ms = m & 2047;
            #pragma unroll
            for (int ni = 0; ni < 2; ++ni) {
                const int d = nb + wn * 32 + ni * 16 + lr;
                ushort4 pk;
                pk.x = f2bf(acc[mi][ni][0]); pk.y = f2bf(acc[mi][ni][1]);
                pk.z = f2bf(acc[mi][ni][2]); pk.w = f2bf(acc[mi][ni][3]);
                *(ushort4*)&vt[((size_t)bb * DIM + d) * SEQ + ms] = pk;
            }
        }
    }
}

// ---------------- L2 normalize; outputs HEAD-MAJOR qn/kn [bh][n][16] ----------------
__global__ __launch_bounds__(256) void l2norm_split(const unsigned short* __restrict__ qkb,
                                                    unsigned short* __restrict__ qn,
                                                    unsigned short* __restrict__ kn)
{
    const int row = blockIdx.x;
    const int t = threadIdx.x;
    const unsigned short* p = qkb + (size_t)row * 512;
    float q = bf2f(p[t]);
    float k = bf2f(p[t + 256]);
    float sq = q * q, sk = k * k;
    #pragma unroll
    for (int off = 32; off > 0; off >>= 1) {
        sq += __shfl_down(sq, off);
        sk += __shfl_down(sk, off);
    }
    __shared__ float sh[8];
    const int wid = t >> 6;
    if ((t & 63) == 0) { sh[wid * 2] = sq; sh[wid * 2 + 1] = sk; }
    __syncthreads();
    sq = sh[0] + sh[2] + sh[4] + sh[6];
    sk = sh[1] + sh[3] + sh[5] + sh[7];
    const float rq = QSCALE / fmaxf(sqrtf(sq), 1e-6f);
    const float rk = 1.0f   / fmaxf(sqrtf(sk), 1e-6f);

    const int b = row >> 11, n = row & 2047;
    const int head = t >> 4, hs = t & 15;
    const size_t o = (((size_t)b * HEADS + head) * SEQ + n) * 16 + hs;
    qn[o] = f2bf(q * rq);
    kn[o] = f2bf(k * rk);
}

// ---------------- attn: 8-wave blocks, wave = (seg, qh, kh)  [R12, best measured] ----------------
template<bool MASK>
__device__ __forceinline__ void segpv(const short8 ak0, const short8 ak1, const short8 bq,
                                      const unsigned short* Vs, int kb, int kh, int hi,
                                      int l31, int qg, f32x16 o[2], float& lp)
{
    const f32x16 z = {};
    short8 pa[4];

    const f32x16 s0 = __builtin_amdgcn_mfma_f32_32x32x16_bf16(ak0, bq, z, 0, 0, 0);
    {
        float p0[16];
        #pragma unroll
        for (int r = 0; r < 16; ++r) {
            float e = __builtin_exp2f(s0[r]);
            if (MASK) {
                const int kl = kb + (r & 3) + 8 * (r >> 2) + 4 * hi;
                e = (kl > qg) ? 0.0f : e;
            }
            p0[r] = e; lp += e;
        }
        #pragma unroll
        for (int g = 0; g < 2; ++g) {
            const int jj = 2 * g;
            unsigned a0, a1, b0, b1;
            asm("v_cvt_pk_bf16_f32 %0, %1, %2" : "=v"(a0) : "v"(p0[4*jj]),     "v"(p0[4*jj + 1]));
            asm("v_cvt_pk_bf16_f32 %0, %1, %2" : "=v"(b0) : "v"(p0[4*jj + 2]), "v"(p0[4*jj + 3]));
            asm("v_cvt_pk_bf16_f32 %0, %1, %2" : "=v"(a1) : "v"(p0[4*jj + 4]), "v"(p0[4*jj + 5]));
            asm("v_cvt_pk_bf16_f32 %0, %1, %2" : "=v"(b1) : "v"(p0[4*jj + 6]), "v"(p0[4*jj + 7]));
            const uint2v r0 = __builtin_amdgcn_permlane32_swap(a0, a1, false, false);
            const uint2v r1 = __builtin_amdgcn_permlane32_swap(b0, b1, false, false);
            union { short8 s; unsigned u[4]; } pu;
            pu.u[0] = r0[0]; pu.u[1] = r1[0]; pu.u[2] = r0[1]; pu.u[3] = r1[1];
            pa[g] = pu.s;
        }
    }
    const f32x16 s1 = __builtin_amdgcn_mfma_f32_32x32x16_bf16(ak1, bq, z, 0, 0, 0);
    {
        float p1[16];
        #pragma unroll
        for (int r = 0; r < 16; ++r) {
            float e = __builtin_exp2f(s1[r]);
            if (MASK) {
                const int kl = kb + 32 + (r & 3) + 8 * (r >> 2) + 4 * hi;
                e = (kl > qg) ? 0.0f : e;
            }
            p1[r] = e; lp += e;
        }
        #pragma unroll
        for (int g = 0; g < 2; ++g) {
            const int jj = 2 * g;
            unsigned a0, a1, b0, b1;
            asm("v_cvt_pk_bf16_f32 %0, %1, %2" : "=v"(a0) : "v"(p1[4*jj]),     "v"(p1[4*jj + 1]));
            asm("v_cvt_pk_bf16_f32 %0, %1, %2" : "=v"(b0) : "v"(p1[4*jj + 2]), "v"(p1[4*jj + 3]));
            asm("v_cvt_pk_bf16_f32 %0, %1, %2" : "=v"(a1) : "v"(p1[4*jj + 4]), "v"(p1[4*jj + 5]));
            asm("v_cvt_pk_bf16_f32 %0, %1, %2" : "=v"(b1) : "v"(p1[4*jj + 6]), "v"(p1[4*jj + 7]));
            const uint2v r0 = __builtin_amdgcn_permlane32_swap(a0, a1, false, false);
            const uint2v r1 = __builtin_amdgcn_permlane32_swap(b0, b1, false, false);
            union { short8 s; unsigned u[4]; } pu;
            pu.u[0] = r0[0]; pu.u[1] = r1[0]; pu.u[2] = r0[1]; pu.u[3] = r1[1];
            pa[2 + g] = pu.s;
        }
    }

    #pragma unroll
    for (int g = 0; g < 4; ++g)
        #pragma unroll
        for (int half = 0; half < 2; ++half) {
            const int row = half * 32 + l31;
            const int slot = (8 * kh + 2 * g + hi) ^ (row & 15);
            const short8 bv = *(const short8*)&Vs[row * 128 + 8 * slot];
            o[half] = __builtin_amdgcn_mfma_f32_32x32x16_bf16(pa[g], bv, o[half], 0, 0, 0);
        }
}

__global__ __launch_bounds__(512, 4) void attn_w8(const unsigned short* __restrict__ qn,
                                                  const unsigned short* __restrict__ kn,
                                                  const unsigned short* __restrict__ vt,
                                                  float* __restrict__ out)
{
    const int L = blockIdx.x;            // 512; L%8 == bh%8 -> XCD-pinned
    const int bh = L & 31;
    const int p  = L >> 5;               // pair {31-p, p}
    const int h = bh & 15, b = bh >> 4;

    const int tid = threadIdx.x, w = tid >> 6, lane = tid & 63;
    const int seg = w >> 2, qh = (w >> 1) & 1, kh = w & 1;
    const int l31 = lane & 31, hi = lane >> 5;

    const int qt  = seg ? p : 31 - p;
    const int nts = (qt >> 1) + 1;       // this wave's active tiles
    const int nt0 = ((31 - p) >> 1) + 1; // loop trip count (heavy)
    const int band = qt * 64 + qh * 32;
    const int qg = band + l31;

    __shared__ __align__(16) unsigned char smem[33792];

    const unsigned short* qbh = qn + (size_t)bh * SEQ * 16;
    const unsigned short* kbh = kn + (size_t)bh * SEQ * 16;

    const short8 bq = *(const short8*)&qbh[qg * 16 + 8 * hi];

    f32x16 o[2] = {};
    float lp = 0.0f;

    const unsigned short* kwin = kbh + (64 * kh + l31) * 16 + 8 * hi;
    short8 ak0 = *(const short8*)(kwin);
    short8 ak1 = *(const short8*)(kwin + 32 * 16);

    const int vsub = lane >> 4, vslot = lane & 15;

#define STAGEV(kt_, buf_) do {                                                                    \
        const int k0_ = (kt_) * 128;                                                              \
        _Pragma("unroll")                                                                         \
        for (int i = 0; i < 2; ++i) {                                                             \
            const int c = 2 * w + i;                                                              \
            const int dh = 4 * c + vsub;                                                          \
            const int so = 8 * (vslot ^ (dh & 15));                                               \
            __builtin_amdgcn_global_load_lds(                                                     \
                (GPTR)&vt[((size_t)b * DIM + h * DH + dh) * SEQ + k0_ + so],                      \
                (LPTR)(smem + (buf_) * 16384 + c * 1024), 16, 0, 0);                              \
        }                                                                                         \
    } while (0)

    STAGEV(0, 0);

    #pragma unroll 1
    for (int kt = 0; kt < nt0; ++kt) {
        short8 an0 = ak0, an1 = ak1;
        if (kt + 1 < nt0) {
            STAGEV(kt + 1, (kt + 1) & 1);
            an0 = *(const short8*)(kwin + (size_t)(kt + 1) * 128 * 16);
            an1 = *(const short8*)(kwin + (size_t)(kt + 1) * 128 * 16 + 32 * 16);
            asm volatile("s_waitcnt vmcnt(4)" ::: "memory");   // drain tile kt only
        } else {
            asm volatile("s_waitcnt vmcnt(0)" ::: "memory");
        }
        __builtin_amdgcn_sched_barrier(0);
        __builtin_amdgcn_s_barrier();        // stage(kt) visible to all waves

        if (kt < nts) {
            const unsigned short* Vs = (const unsigned short*)(smem + (kt & 1) * 16384);
            const int kb = kt * 128 + 64 * kh;
            __builtin_amdgcn_s_setprio(1);
            if (kt < nts - 1) {
                segpv<false>(ak0, ak1, bq, Vs, kb, kh, hi, l31, qg, o, lp);
            } else if (kb <= band + 31) {
                if (kb + 63 <= band) segpv<false>(ak0, ak1, bq, Vs, kb, kh, hi, l31, qg, o, lp);
                else                 segpv<true >(ak0, ak1, bq, Vs, kb, kh, hi, l31, qg, o, lp);
            }
            __builtin_amdgcn_s_setprio(0);
        }

        ak0 = an0; ak1 = an1;
        __builtin_amdgcn_s_barrier();        // all waves done reading buf kt
    }
#undef STAGEV

    // ---- epilogue: per-seg 2-way kh merge, normalize, store ----
    lp += __shfl_xor(lp, 32);

    __syncthreads();
    float* Os = (float*)(smem + seg * 16384);
    float* Ls = (float*)(smem + 32768 + seg * 512);

    if (kh == 1) {
        #pragma unroll
        for (int half = 0; half < 2; ++half)
            #pragma unroll
            for (int r = 0; r < 16; ++r) {
                const int q = (r & 3) + 8 * (r >> 2) + 4 * hi;
                Os[(qh * 32 + q) * 64 + half * 32 + l31] = o[half][r];
            }
        Ls[qh * 64 + lane] = lp;
    }
    __syncthreads();
    if (kh == 0) {
        const float lt = lp + Ls[qh * 64 + lane];
        const float inv = 1.0f / fmaxf(lt, 1e-6f);
        #pragma unroll
        for (int r = 0; r < 16; ++r) {
            const int q = (r & 3) + 8 * (r >> 2) + 4 * hi;
            const float iv = __shfl(inv, q);
            #pragma unroll
            for (int half = 0; half < 2; ++half) {
                const float v = (o[half][r] + Os[(qh * 32 + q) * 64 + half * 32 + l31]) * iv;
                __builtin_nontemporal_store(v,
                    &out[((size_t)b * SEQ + band + q) * DIM + h * DH + half * 32 + l31]);
            }
        }
    }
}

extern "C" void kernel_launch(void* const* d_in, const int* in_sizes, int n_in,
                              void* d_out, int out_size, void* d_ws, size_t ws_size,
                              hipStream_t stream)
{
    const float* x   = (const float*)d_in[0];
    // d_in[1] = mask (causal, analytic)
    const float* Wqk = (const float*)d_in[2];
    const float* Wv  = (const float*)d_in[3];
    float* out = (float*)d_out;

    // workspace: xb 8MB | qkb 4MB | vt 8MB | wcat 3MB ; qn/kn (head-major) overlay xb
    unsigned short* xb   = (unsigned short*)d_ws;
    unsigned short* qkb  = xb  + (size_t)MROWS * DIM;
    unsigned short* vt   = qkb + (size_t)MROWS * 512;
    unsigned short* wcat = vt  + (size_t)BATCH * DIM * SEQ;
    unsigned short* qn = xb;                               // [32 bh][2048][16]
    unsigned short* kn = xb + (size_t)32 * SEQ * 16;

    conv3<<<5632, 256, 0, stream>>>(x, Wqk, Wv, xb, wcat);
    gemm_mfma<<<768, 256, 0, stream>>>(xb, wcat, qkb, vt);
    l2norm_split<<<MROWS, 256, 0, stream>>>(qkb, qn, kn);
    attn_w8<<<512, 512, 0, stream>>>(qn, kn, vt, out);
}

// Round 16
// 65.856 us; speedup vs baseline: 1.3213x; 1.0230x over previous
//
#include <hip/hip_runtime.h>
#include <math.h>

// Problem constants
#define BATCH 2
#define SEQ   2048
#define DIM   1024
#define RANK  256
#define HEADS 16
#define HS    16
#define DH    64
#define MROWS 4096

#define QSCALE 0.36067376f   // 0.25 * log2(e), folded into normalized q

typedef __attribute__((ext_vector_type(8)))  short    short8;   // 8 bf16
typedef __attribute__((ext_vector_type(4)))  float    f32x4;
typedef __attribute__((ext_vector_type(16))) float    f32x16;
typedef __attribute__((ext_vector_type(2)))  unsigned uint2v;

#define GPTR const __attribute__((address_space(1))) unsigned int*
#define LPTR __attribute__((address_space(3))) unsigned int*

__device__ __forceinline__ unsigned short f2bf(float f) {
    union { float f; unsigned u; } v; v.f = f;
    return (unsigned short)((v.u + 0x7FFFu + ((v.u >> 16) & 1u)) >> 16);  // RNE
}
__device__ __forceinline__ float bf2f(unsigned short h) {
    union { unsigned u; float f; } v; v.u = ((unsigned)h) << 16;
    return v.f;
}

// exp2(x) for |x| <= 0.361: cubic minimax-ish (Taylor), rel err ~1.6e-4 << bf16 ulp
__device__ __forceinline__ float exp2_poly(float x) {
    return fmaf(x, fmaf(x, fmaf(x, 0.05550411f, 0.24022651f), 0.69314718f), 1.0f);
}

// ---------------- fused f32 -> bf16 convert for x, Wqk, Wv ----------------
#define XQ   1048576
#define WQKQ 131072
#define WVQ  262144
__global__ __launch_bounds__(256) void conv3(const float* __restrict__ x,
                                             const float* __restrict__ wqk,
                                             const float* __restrict__ wv,
                                             unsigned short* __restrict__ xb,
                                             unsigned short* __restrict__ wcat)
{
    const int i = blockIdx.x * 256 + threadIdx.x;
    const float* src; unsigned short* dst; int j;
    if (i < XQ)              { src = x;   dst = xb;   j = i; }
    else if (i < XQ + WQKQ)  { src = wqk; dst = wcat; j = i - XQ; }
    else                     { src = wv;  dst = wcat + (size_t)4 * WQKQ; j = i - XQ - WQKQ; }
    float4 v = ((const float4*)src)[j];
    ushort4 o; o.x = f2bf(v.x); o.y = f2bf(v.y); o.z = f2bf(v.z); o.w = f2bf(v.w);
    ((ushort4*)dst)[j] = o;
}

// ---------------- MFMA GEMM: 128x64, BK=64, DBUF + counted vmcnt, XCD-local ----------------
__global__ __launch_bounds__(256, 3) void gemm_mfma(const unsigned short* __restrict__ A,
                                                    const unsigned short* __restrict__ W,
                                                    unsigned short* __restrict__ qkb,
                                                    unsigned short* __restrict__ vt)
{
    __shared__ __align__(16) unsigned short Alds[2][128 * 64];  // 32 KB
    __shared__ __align__(16) unsigned short Blds[2][64 * 64];   // 16 KB

    const int tid = threadIdx.x;
    const int w = tid >> 6, lane = tid & 63;
    const int lr = lane & 15, lg = lane >> 4;
    const int wm = w >> 1, wn = w & 1;

    const int Lf = blockIdx.x;                 // 768 blocks
    const int xcd = Lf & 7;
    const int i5 = Lf >> 3;                    // 0..95 within XCD
    const int bm = (4 * xcd + (i5 & 3)) * 128; // m-tiles 4x..4x+3
    const int bn = (i5 >> 2) * 64;             // all 24 n-tiles

    const int rs = lane >> 3, cs = lane & 7;

    f32x4 acc[4][2] = {};

#define STAGEG(kt_, buf_) do {                                                        \
        const int k0_ = (kt_) * 64;                                                   \
        _Pragma("unroll")                                                             \
        for (int i = 0; i < 4; ++i) {                                                 \
            const int r = w * 32 + i * 8 + rs;                                        \
            __builtin_amdgcn_global_load_lds(                                         \
                (GPTR)&A[(size_t)(bm + r) * 1024 + k0_ + 8 * (cs ^ (r & 7))],         \
                (LPTR)&Alds[buf_][(w * 32 + i * 8) * 64], 16, 0, 0);                  \
        }                                                                             \
        _Pragma("unroll")                                                             \
        for (int i = 0; i < 2; ++i) {                                                 \
            const int r = w * 16 + i * 8 + rs;                                        \
            __builtin_amdgcn_global_load_lds(                                         \
                (GPTR)&W[(size_t)(bn + r) * 1024 + k0_ + 8 * (cs ^ (r & 7))],         \
                (LPTR)&Blds[buf_][(w * 16 + i * 8) * 64], 16, 0, 0);                  \
        }                                                                             \
    } while (0)

    STAGEG(0, 0);

    #pragma unroll 1
    for (int kt = 0; kt < 16; ++kt) {
        if (kt + 1 < 16) {
            STAGEG(kt + 1, (kt + 1) & 1);
            asm volatile("s_waitcnt vmcnt(6)" ::: "memory");   // drain tile kt only
        } else {
            asm volatile("s_waitcnt vmcnt(0)" ::: "memory");
        }
        __builtin_amdgcn_sched_barrier(0);
        __builtin_amdgcn_s_barrier();

        const int buf = kt & 1;
        #pragma unroll
        for (int kk = 0; kk < 2; ++kk) {
            short8 af[4], bfr[2];
            #pragma unroll
            for (int mi = 0; mi < 4; ++mi) {
                const int row = wm * 64 + mi * 16 + lr;
                af[mi] = *(const short8*)&Alds[buf][row * 64 + 8 * ((kk * 4 + lg) ^ (row & 7))];
            }
            #pragma unroll
            for (int ni = 0; ni < 2; ++ni) {
                const int row = wn * 32 + ni * 16 + lr;
                bfr[ni] = *(const short8*)&Blds[buf][row * 64 + 8 * ((kk * 4 + lg) ^ (row & 7))];
            }
            #pragma unroll
            for (int mi = 0; mi < 4; ++mi)
                #pragma unroll
                for (int ni = 0; ni < 2; ++ni)
                    acc[mi][ni] = __builtin_amdgcn_mfma_f32_16x16x32_bf16(af[mi], bfr[ni], acc[mi][ni], 0, 0, 0);
        }
        __builtin_amdgcn_s_barrier();   // all waves done with buf before restage
    }
#undef STAGEG

    if (bn < 512) {
        #pragma unroll
        for (int mi = 0; mi < 4; ++mi) {
            const int rbase = bm + wm * 64 + mi * 16 + lg * 4;
            #pragma unroll
            for (int ni = 0; ni < 2; ++ni) {
                const int col = bn + wn * 32 + ni * 16 + lr;
                #pragma unroll
                for (int r = 0; r < 4; ++r)
                    qkb[(size_t)(rbase + r) * 512 + col] = f2bf(acc[mi][ni][r]);
            }
        }
    } else {
        const int nb = bn - 512;
        #pragma unroll
        for (int mi = 0; mi < 4; ++mi) {
            const int m = bm + wm * 64 + mi * 16 + lg * 4;
            const int bb = m >> 11, ms = m & 2047;
            #pragma unroll
            for (int ni = 0; ni < 2; ++ni) {
                const int d = nb + wn * 32 + ni * 16 + lr;
                ushort4 pk;
                pk.x = f2bf(acc[mi][ni][0]); pk.y = f2bf(acc[mi][ni][1]);
                pk.z = f2bf(acc[mi][ni][2]); pk.w = f2bf(acc[mi][ni][3]);
                *(ushort4*)&vt[((size_t)bb * DIM + d) * SEQ + ms] = pk;
            }
        }
    }
}

// ---------------- L2 normalize; outputs HEAD-MAJOR qn/kn [bh][n][16] ----------------
__global__ __launch_bounds__(256) void l2norm_split(const unsigned short* __restrict__ qkb,
                                                    unsigned short* __restrict__ qn,
                                                    unsigned short* __restrict__ kn)
{
    const int row = blockIdx.x;
    const int t = threadIdx.x;
    const unsigned short* p = qkb + (size_t)row * 512;
    float q = bf2f(p[t]);
    float k = bf2f(p[t + 256]);
    float sq = q * q, sk = k * k;
    #pragma unroll
    for (int off = 32; off > 0; off >>= 1) {
        sq += __shfl_down(sq, off);
        sk += __shfl_down(sk, off);
    }
    __shared__ float sh[8];
    const int wid = t >> 6;
    if ((t & 63) == 0) { sh[wid * 2] = sq; sh[wid * 2 + 1] = sk; }
    __syncthreads();
    sq = sh[0] + sh[2] + sh[4] + sh[6];
    sk = sh[1] + sh[3] + sh[5] + sh[7];
    const float rq = QSCALE / fmaxf(sqrtf(sq), 1e-6f);
    const float rk = 1.0f   / fmaxf(sqrtf(sk), 1e-6f);

    const int b = row >> 11, n = row & 2047;
    const int head = t >> 4, hs = t & 15;
    const size_t o = (((size_t)b * HEADS + head) * SEQ + n) * 16 + hs;
    qn[o] = f2bf(q * rq);
    kn[o] = f2bf(k * rk);
}

// ---------------- attn: 4 waves = (seg, kh), 64 q-rows/wave, shared V frags ----------------
// Block = pair {31-p, p} x 256 threads. Each wave owns BOTH q-halves of its
// segment: V fragments read from LDS ONCE per tile, reused for both q-halves
// (block LDS traffic halved vs R12). Softmax exp via cubic poly (no trans ops).

template<bool MASK>
__device__ __forceinline__ void qpv(const short8 ak0, const short8 ak1, const short8 bq,
                                    const short8 vb[4][2], int kb, int hi, int qg,
                                    f32x16 o[2], float& lp)
{
    const f32x16 z = {};
    short8 pa[4];

    const f32x16 s0 = __builtin_amdgcn_mfma_f32_32x32x16_bf16(ak0, bq, z, 0, 0, 0);
    const f32x16 s1 = __builtin_amdgcn_mfma_f32_32x32x16_bf16(ak1, bq, z, 0, 0, 0);

    float p0[16], p1[16];
    #pragma unroll
    for (int r = 0; r < 16; ++r) {
        float e0 = exp2_poly(s0[r]);
        float e1 = exp2_poly(s1[r]);
        if (MASK) {
            const int kl = kb + (r & 3) + 8 * (r >> 2) + 4 * hi;
            e0 = (kl > qg) ? 0.0f : e0;
            e1 = (kl + 32 > qg) ? 0.0f : e1;
        }
        p0[r] = e0; p1[r] = e1;
        lp += e0 + e1;
    }

    #pragma unroll
    for (int g = 0; g < 4; ++g) {
        const float* pc = (g < 2) ? p0 : p1;
        const int jj = 2 * (g & 1);
        unsigned a0, a1, b0, b1;
        asm("v_cvt_pk_bf16_f32 %0, %1, %2" : "=v"(a0) : "v"(pc[4*jj]),     "v"(pc[4*jj + 1]));
        asm("v_cvt_pk_bf16_f32 %0, %1, %2" : "=v"(b0) : "v"(pc[4*jj + 2]), "v"(pc[4*jj + 3]));
        asm("v_cvt_pk_bf16_f32 %0, %1, %2" : "=v"(a1) : "v"(pc[4*jj + 4]), "v"(pc[4*jj + 5]));
        asm("v_cvt_pk_bf16_f32 %0, %1, %2" : "=v"(b1) : "v"(pc[4*jj + 6]), "v"(pc[4*jj + 7]));
        const uint2v r0 = __builtin_amdgcn_permlane32_swap(a0, a1, false, false);
        const uint2v r1 = __builtin_amdgcn_permlane32_swap(b0, b1, false, false);
        union { short8 s; unsigned u[4]; } pu;
        pu.u[0] = r0[0]; pu.u[1] = r1[0]; pu.u[2] = r0[1]; pu.u[3] = r1[1];
        pa[g] = pu.s;
    }

    #pragma unroll
    for (int g = 0; g < 4; ++g)
        #pragma unroll
        for (int half = 0; half < 2; ++half)
            o[half] = __builtin_amdgcn_mfma_f32_32x32x16_bf16(pa[g], vb[g][half], o[half], 0, 0, 0);
}

// per-q-half last-tile dispatch
__device__ __forceinline__ void qdisp(bool last, const short8 ak0, const short8 ak1,
                                      const short8 bq, const short8 vb[4][2], int kb,
                                      int hi, int qmin, int qg,
                                      f32x16 o[2], float& lp)
{
    if (!last) {
        qpv<false>(ak0, ak1, bq, vb, kb, hi, qg, o, lp);
    } else if (kb <= qmin + 31) {
        if (kb + 63 <= qmin) qpv<false>(ak0, ak1, bq, vb, kb, hi, qg, o, lp);
        else                 qpv<true >(ak0, ak1, bq, vb, kb, hi, qg, o, lp);
    }
}

__global__ __launch_bounds__(256, 2) void attn_q64(const unsigned short* __restrict__ qn,
                                                   const unsigned short* __restrict__ kn,
                                                   const unsigned short* __restrict__ vt,
                                                   float* __restrict__ out)
{
    const int L = blockIdx.x;            // 512; L%8 == bh%8 -> XCD-pinned
    const int bh = L & 31;
    const int p  = L >> 5;               // pair {31-p, p}
    const int h = bh & 15, b = bh >> 4;

    const int tid = threadIdx.x, w = tid >> 6, lane = tid & 63;
    const int seg = w >> 1, kh = w & 1;
    const int l31 = lane & 31, hi = lane >> 5;

    const int qt  = seg ? p : 31 - p;
    const int nts = (qt >> 1) + 1;       // this wave's active tiles
    const int nt0 = ((31 - p) >> 1) + 1; // loop trip count (heavy)
    const int qmin0 = qt * 64, qmin1 = qt * 64 + 32;
    const int qg0 = qmin0 + l31, qg1 = qmin1 + l31;

    // V dbuf 2x16KB (32 KB); epilogue overlay Os 32K | Ls 1K
    __shared__ __align__(16) unsigned char smem[33792];

    const unsigned short* qbh = qn + (size_t)bh * SEQ * 16;
    const unsigned short* kbh = kn + (size_t)bh * SEQ * 16;

    const short8 bq0 = *(const short8*)&qbh[qg0 * 16 + 8 * hi];
    const short8 bq1 = *(const short8*)&qbh[qg1 * 16 + 8 * hi];

    f32x16 o0[2] = {}, o1[2] = {};
    float lp0 = 0.0f, lp1 = 0.0f;

    const unsigned short* kwin = kbh + (64 * kh + l31) * 16 + 8 * hi;
    short8 ak0 = *(const short8*)(kwin);
    short8 ak1 = *(const short8*)(kwin + 32 * 16);

    const int vsub = lane >> 4, vslot = lane & 15;

#define STAGEV(kt_, buf_) do {                                                                    \
        const int k0_ = (kt_) * 128;                                                              \
        _Pragma("unroll")                                                                         \
        for (int i = 0; i < 4; ++i) {                                                             \
            const int c = 4 * w + i;                                                              \
            const int dh = 4 * c + vsub;                                                          \
            const int so = 8 * (vslot ^ (dh & 15));                                               \
            __builtin_amdgcn_global_load_lds(                                                     \
                (GPTR)&vt[((size_t)b * DIM + h * DH + dh) * SEQ + k0_ + so],                      \
                (LPTR)(smem + (buf_) * 16384 + c * 1024), 16, 0, 0);                              \
        }                                                                                         \
    } while (0)

    STAGEV(0, 0);

    #pragma unroll 1
    for (int kt = 0; kt < nt0; ++kt) {
        short8 an0 = ak0, an1 = ak1;
        if (kt + 1 < nt0) {
            STAGEV(kt + 1, (kt + 1) & 1);
            an0 = *(const short8*)(kwin + (size_t)(kt + 1) * 128 * 16);
            an1 = *(const short8*)(kwin + (size_t)(kt + 1) * 128 * 16 + 32 * 16);
            asm volatile("s_waitcnt vmcnt(6)" ::: "memory");   // drain tile kt only
        } else {
            asm volatile("s_waitcnt vmcnt(0)" ::: "memory");
        }
        __builtin_amdgcn_sched_barrier(0);
        __builtin_amdgcn_s_barrier();        // stage(kt) visible to all waves

        if (kt < nts) {
            const unsigned short* Vs = (const unsigned short*)(smem + (kt & 1) * 16384);
            const int kb = kt * 128 + 64 * kh;

            // V fragments: read ONCE, reused for both q-halves
            short8 vb[4][2];
            #pragma unroll
            for (int g = 0; g < 4; ++g)
                #pragma unroll
                for (int half = 0; half < 2; ++half) {
                    const int row = half * 32 + l31;
                    const int slot = (8 * kh + 2 * g + hi) ^ (row & 15);
                    vb[g][half] = *(const short8*)&Vs[row * 128 + 8 * slot];
                }

            const bool last = (kt == nts - 1);
            __builtin_amdgcn_s_setprio(1);
            qdisp(last, ak0, ak1, bq0, vb, kb, hi, qmin0, qg0, o0, lp0);
            qdisp(last, ak0, ak1, bq1, vb, kb, hi, qmin1, qg1, o1, lp1);
            __builtin_amdgcn_s_setprio(0);
        }

        ak0 = an0; ak1 = an1;
        __builtin_amdgcn_s_barrier();        // all waves done reading buf kt
    }
#undef STAGEV

    // ---- epilogue: 2-way kh merge per (seg, q-half), normalize, store ----
    lp0 += __shfl_xor(lp0, 32);
    lp1 += __shfl_xor(lp1, 32);

    __syncthreads();                         // V dbuf dead; reuse smem
    float* Os = (float*)smem;                // [2 seg][64 q][64 lane] = 32 KB
    float* Ls = (float*)(smem + 32768);      // [2 seg][2 qi][64 lane] = 1 KB

    if (kh == 1) {
        #pragma unroll
        for (int half = 0; half < 2; ++half)
            #pragma unroll
            for (int r = 0; r < 16; ++r) {
                const int q = (r & 3) + 8 * (r >> 2) + 4 * hi;
                Os[(seg * 64 + q) * 64 + half * 32 + l31]      = o0[half][r];
                Os[(seg * 64 + 32 + q) * 64 + half * 32 + l31] = o1[half][r];
            }
        Ls[seg * 128 + lane]      = lp0;
        Ls[seg * 128 + 64 + lane] = lp1;
    }
    __syncthreads();
    if (kh == 0) {
        float lt0 = lp0 + Ls[seg * 128 + lane];
        float lt1 = lp1 + Ls[seg * 128 + 64 + lane];
        const float inv0 = 1.0f / fmaxf(lt0, 1e-6f);
        const float inv1 = 1.0f / fmaxf(lt1, 1e-6f);
        #pragma unroll
        for (int r = 0; r < 16; ++r) {
            const int q = (r & 3) + 8 * (r >> 2) + 4 * hi;
            const float iv0 = __shfl(inv0, q);
            const float iv1 = __shfl(inv1, q);
            #pragma unroll
            for (int half = 0; half < 2; ++half) {
                const float v0 = (o0[half][r] + Os[(seg * 64 + q) * 64 + half * 32 + l31]) * iv0;
                const float v1 = (o1[half][r] + Os[(seg * 64 + 32 + q) * 64 + half * 32 + l31]) * iv1;
                __builtin_nontemporal_store(v0,
                    &out[((size_t)b * SEQ + qmin0 + q) * DIM + h * DH + half * 32 + l31]);
                __builtin_nontemporal_store(v1,
                    &out[((size_t)b * SEQ + qmin1 + q) * DIM + h * DH + half * 32 + l31]);
            }
        }
    }
}

extern "C" void kernel_launch(void* const* d_in, const int* in_sizes, int n_in,
                              void* d_out, int out_size, void* d_ws, size_t ws_size,
                              hipStream_t stream)
{
    const float* x   = (const float*)d_in[0];
    // d_in[1] = mask (causal, analytic)
    const float* Wqk = (const float*)d_in[2];
    const float* Wv  = (const float*)d_in[3];
    float* out = (float*)d_out;

    // workspace: xb 8MB | qkb 4MB | vt 8MB | wcat 3MB ; qn/kn (head-major) overlay xb
    unsigned short* xb   = (unsigned short*)d_ws;
    unsigned short* qkb  = xb  + (size_t)MROWS * DIM;
    unsigned short* vt   = qkb + (size_t)MROWS * 512;
    unsigned short* wcat = vt  + (size_t)BATCH * DIM * SEQ;
    unsigned short* qn = xb;                               // [32 bh][2048][16]
    unsigned short* kn = xb + (size_t)32 * SEQ * 16;

    conv3<<<5632, 256, 0, stream>>>(x, Wqk, Wv, xb, wcat);
    gemm_mfma<<<768, 256, 0, stream>>>(xb, wcat, qkb, vt);
    l2norm_split<<<MROWS, 256, 0, stream>>>(qkb, qn, kn);
    attn_q64<<<512, 256, 0, stream>>>(qn, kn, vt, out);
}

// Round 17
// 62.942 us; speedup vs baseline: 1.3825x; 1.0463x over previous
//
#include <hip/hip_runtime.h>
#include <math.h>

// Problem constants
#define BATCH 2
#define SEQ   2048
#define DIM   1024
#define RANK  256
#define HEADS 16
#define HS    16
#define DH    64
#define MROWS 4096

#define QSCALE 0.36067376f   // 0.25 * log2(e), folded into rq at attn prologue

typedef __attribute__((ext_vector_type(8)))  short    short8;   // 8 bf16
typedef __attribute__((ext_vector_type(4)))  float    f32x4;
typedef __attribute__((ext_vector_type(16))) float    f32x16;
typedef __attribute__((ext_vector_type(2)))  unsigned uint2v;

#define GPTR const __attribute__((address_space(1))) unsigned int*
#define LPTR __attribute__((address_space(3))) unsigned int*

__device__ __forceinline__ unsigned short f2bf(float f) {
    union { float f; unsigned u; } v; v.f = f;
    return (unsigned short)((v.u + 0x7FFFu + ((v.u >> 16) & 1u)) >> 16);  // RNE
}
__device__ __forceinline__ float bf2f(unsigned short h) {
    union { unsigned u; float f; } v; v.u = ((unsigned)h) << 16;
    return v.f;
}

// exp2(x) for |x| <= ~0.365: cubic, rel err ~1.6e-4 << bf16 ulp
__device__ __forceinline__ float exp2_poly(float x) {
    return fmaf(x, fmaf(x, fmaf(x, 0.05550411f, 0.24022651f), 0.69314718f), 1.0f);
}

// scale a bf16x8 fragment by a scalar (unpack, mul, repack RNE)
__device__ __forceinline__ short8 fold8(short8 v, float s) {
    union { short8 v8; unsigned short us[8]; } u; u.v8 = v;
    float f[8];
    #pragma unroll
    for (int j = 0; j < 8; ++j) f[j] = bf2f(u.us[j]) * s;
    unsigned w0, w1, w2, w3;
    asm("v_cvt_pk_bf16_f32 %0, %1, %2" : "=v"(w0) : "v"(f[0]), "v"(f[1]));
    asm("v_cvt_pk_bf16_f32 %0, %1, %2" : "=v"(w1) : "v"(f[2]), "v"(f[3]));
    asm("v_cvt_pk_bf16_f32 %0, %1, %2" : "=v"(w2) : "v"(f[4]), "v"(f[5]));
    asm("v_cvt_pk_bf16_f32 %0, %1, %2" : "=v"(w3) : "v"(f[6]), "v"(f[7]));
    union { short8 v8; unsigned uu[4]; } o;
    o.uu[0] = w0; o.uu[1] = w1; o.uu[2] = w2; o.uu[3] = w3;
    return o.v8;
}

// ---------------- fused f32 -> bf16 convert for x, Wqk, Wv + zero norm bufs ----------------
#define XQ   1048576
#define WQKQ 131072
#define WVQ  262144
#define NTOT (XQ + WQKQ + WVQ)    // 1441792 = 5632 * 256
__global__ __launch_bounds__(256) void conv3(const float* __restrict__ x,
                                             const float* __restrict__ wqk,
                                             const float* __restrict__ wv,
                                             unsigned short* __restrict__ xb,
                                             unsigned short* __restrict__ wcat,
                                             float* __restrict__ norms)
{
    const int i = blockIdx.x * 256 + threadIdx.x;
    if (i >= NTOT) {                          // last 8 blocks: zero nq|nk (8192 f32)
        const int j = i - NTOT;               // 0..2047 float4s
        ((float4*)norms)[j] = make_float4(0.f, 0.f, 0.f, 0.f);
        return;
    }
    const float* src; unsigned short* dst; int j;
    if (i < XQ)              { src = x;   dst = xb;   j = i; }
    else if (i < XQ + WQKQ)  { src = wqk; dst = wcat; j = i - XQ; }
    else                     { src = wv;  dst = wcat + (size_t)4 * WQKQ; j = i - XQ - WQKQ; }
    float4 v = ((const float4*)src)[j];
    ushort4 o; o.x = f2bf(v.x); o.y = f2bf(v.y); o.z = f2bf(v.z); o.w = f2bf(v.w);
    ((ushort4*)dst)[j] = o;
}

// ---------------- MFMA GEMM: 128x64, BK=64, DBUF + counted vmcnt, XCD-local ----------------
// Epilogue: bn<512 -> write q/k HEAD-MAJOR [bh][n][16] RAW (no normalization) and
// accumulate per-row sum-of-squares into nq/nk (shfl-reduced, 1 atomic/row-half).
// bn>=512 -> vt transposed as before. Normalization commutes into attn scores.
__global__ __launch_bounds__(256, 3) void gemm_mfma(const unsigned short* __restrict__ A,
                                                    const unsigned short* __restrict__ W,
                                                    unsigned short* __restrict__ qh,
                                                    unsigned short* __restrict__ khm,
                                                    unsigned short* __restrict__ vt,
                                                    float* __restrict__ nq,
                                                    float* __restrict__ nk)
{
    __shared__ __align__(16) unsigned short Alds[2][128 * 64];  // 32 KB
    __shared__ __align__(16) unsigned short Blds[2][64 * 64];   // 16 KB

    const int tid = threadIdx.x;
    const int w = tid >> 6, lane = tid & 63;
    const int lr = lane & 15, lg = lane >> 4;
    const int wm = w >> 1, wn = w & 1;

    const int Lf = blockIdx.x;                 // 768 blocks
    const int xcd = Lf & 7;
    const int i5 = Lf >> 3;                    // 0..95 within XCD
    const int bm = (4 * xcd + (i5 & 3)) * 128; // m-tiles 4x..4x+3
    const int bn = (i5 >> 2) * 64;             // all 24 n-tiles

    const int rs = lane >> 3, cs = lane & 7;

    f32x4 acc[4][2] = {};

#define STAGEG(kt_, buf_) do {                                                        \
        const int k0_ = (kt_) * 64;                                                   \
        _Pragma("unroll")                                                             \
        for (int i = 0; i < 4; ++i) {                                                 \
            const int r = w * 32 + i * 8 + rs;                                        \
            __builtin_amdgcn_global_load_lds(                                         \
                (GPTR)&A[(size_t)(bm + r) * 1024 + k0_ + 8 * (cs ^ (r & 7))],         \
                (LPTR)&Alds[buf_][(w * 32 + i * 8) * 64], 16, 0, 0);                  \
        }                                                                             \
        _Pragma("unroll")                                                             \
        for (int i = 0; i < 2; ++i) {                                                 \
            const int r = w * 16 + i * 8 + rs;                                        \
            __builtin_amdgcn_global_load_lds(                                         \
                (GPTR)&W[(size_t)(bn + r) * 1024 + k0_ + 8 * (cs ^ (r & 7))],         \
                (LPTR)&Blds[buf_][(w * 16 + i * 8) * 64], 16, 0, 0);                  \
        }                                                                             \
    } while (0)

    STAGEG(0, 0);

    #pragma unroll 1
    for (int kt = 0; kt < 16; ++kt) {
        if (kt + 1 < 16) {
            STAGEG(kt + 1, (kt + 1) & 1);
            asm volatile("s_waitcnt vmcnt(6)" ::: "memory");   // drain tile kt only
        } else {
            asm volatile("s_waitcnt vmcnt(0)" ::: "memory");
        }
        __builtin_amdgcn_sched_barrier(0);
        __builtin_amdgcn_s_barrier();

        const int buf = kt & 1;
        #pragma unroll
        for (int kk = 0; kk < 2; ++kk) {
            short8 af[4], bfr[2];
            #pragma unroll
            for (int mi = 0; mi < 4; ++mi) {
                const int row = wm * 64 + mi * 16 + lr;
                af[mi] = *(const short8*)&Alds[buf][row * 64 + 8 * ((kk * 4 + lg) ^ (row & 7))];
            }
            #pragma unroll
            for (int ni = 0; ni < 2; ++ni) {
                const int row = wn * 32 + ni * 16 + lr;
                bfr[ni] = *(const short8*)&Blds[buf][row * 64 + 8 * ((kk * 4 + lg) ^ (row & 7))];
            }
            #pragma unroll
            for (int mi = 0; mi < 4; ++mi)
                #pragma unroll
                for (int ni = 0; ni < 2; ++ni)
                    acc[mi][ni] = __builtin_amdgcn_mfma_f32_16x16x32_bf16(af[mi], bfr[ni], acc[mi][ni], 0, 0, 0);
        }
        __builtin_amdgcn_s_barrier();   // all waves done with buf before restage
    }
#undef STAGEG

    if (bn < 512) {
        const bool isq = (bn < 256);
        float* nbuf = isq ? nq : nk;
        unsigned short* dst = isq ? qh : khm;
        #pragma unroll
        for (int mi = 0; mi < 4; ++mi) {
            const int rbase = bm + wm * 64 + mi * 16 + lg * 4;
            // per-row sum of squares over this wave's 32 cols (f32, pre-rounding)
            #pragma unroll
            for (int r = 0; r < 4; ++r) {
                float t = acc[mi][0][r] * acc[mi][0][r] + acc[mi][1][r] * acc[mi][1][r];
                t += __shfl_xor(t, 1);
                t += __shfl_xor(t, 2);
                t += __shfl_xor(t, 4);
                t += __shfl_xor(t, 8);
                if (lr == 0) atomicAdd(&nbuf[rbase + r], t);
            }
            // head-major raw bf16 store: [bh][n][16]
            #pragma unroll
            for (int ni = 0; ni < 2; ++ni) {
                const int col = bn + wn * 32 + ni * 16 + lr;
                const int h = (col & 255) >> 4;
                #pragma unroll
                for (int r = 0; r < 4; ++r) {
                    const int row = rbase + r;
                    const int bb = row >> 11, ns = row & 2047;
                    dst[(((size_t)bb * HEADS + h) * SEQ + ns) * 16 + lr] = f2bf(acc[mi][ni][r]);
                }
            }
        }
    } else {
        const int nb = bn - 512;
        #pragma unroll
        for (int mi = 0; mi < 4; ++mi) {
            const int m = bm + wm * 64 + mi * 16 + lg * 4;
            const int bb = m >> 11, ms = m & 2047;
            #pragma unroll
            for (int ni = 0; ni < 2; ++ni) {
                const int d = nb + wn * 32 + ni * 16 + lr;
                ushort4 pk;
                pk.x = f2bf(acc[mi][ni][0]); pk.y = f2bf(acc[mi][ni][1]);
                pk.z = f2bf(acc[mi][ni][2]); pk.w = f2bf(acc[mi][ni][3]);
                *(ushort4*)&vt[((size_t)bb * DIM + d) * SEQ + ms] = pk;
            }
        }
    }
}

// ---------------- attn: 4 waves = (seg, kh), 64 q/wave, score-side normalization ----------------
// Inputs are RAW head-major q/k + per-row sum-of-squares. rq folded into Q-frag
// once per wave; rk folded into K-frags per tile (per-lane scalar, off V-wait path).

template<bool MASK>
__device__ __forceinline__ void qpv(const short8 ak0, const short8 ak1, const short8 bq,
                                    const short8 vb[4][2], int kb, int hi, int qg,
                                    f32x16 o[2], float& lp)
{
    const f32x16 z = {};
    short8 pa[4];

    const f32x16 s0 = __builtin_amdgcn_mfma_f32_32x32x16_bf16(ak0, bq, z, 0, 0, 0);
    const f32x16 s1 = __builtin_amdgcn_mfma_f32_32x32x16_bf16(ak1, bq, z, 0, 0, 0);

    float p0[16], p1[16];
    #pragma unroll
    for (int r = 0; r < 16; ++r) {
        float e0 = exp2_poly(s0[r]);
        float e1 = exp2_poly(s1[r]);
        if (MASK) {
            const int kl = kb + (r & 3) + 8 * (r >> 2) + 4 * hi;
            e0 = (kl > qg) ? 0.0f : e0;
            e1 = (kl + 32 > qg) ? 0.0f : e1;
        }
        p0[r] = e0; p1[r] = e1;
        lp += e0 + e1;
    }

    #pragma unroll
    for (int g = 0; g < 4; ++g) {
        const float* pc = (g < 2) ? p0 : p1;
        const int jj = 2 * (g & 1);
        unsigned a0, a1, b0, b1;
        asm("v_cvt_pk_bf16_f32 %0, %1, %2" : "=v"(a0) : "v"(pc[4*jj]),     "v"(pc[4*jj + 1]));
        asm("v_cvt_pk_bf16_f32 %0, %1, %2" : "=v"(b0) : "v"(pc[4*jj + 2]), "v"(pc[4*jj + 3]));
        asm("v_cvt_pk_bf16_f32 %0, %1, %2" : "=v"(a1) : "v"(pc[4*jj + 4]), "v"(pc[4*jj + 5]));
        asm("v_cvt_pk_bf16_f32 %0, %1, %2" : "=v"(b1) : "v"(pc[4*jj + 6]), "v"(pc[4*jj + 7]));
        const uint2v r0 = __builtin_amdgcn_permlane32_swap(a0, a1, false, false);
        const uint2v r1 = __builtin_amdgcn_permlane32_swap(b0, b1, false, false);
        union { short8 s; unsigned u[4]; } pu;
        pu.u[0] = r0[0]; pu.u[1] = r1[0]; pu.u[2] = r0[1]; pu.u[3] = r1[1];
        pa[g] = pu.s;
    }

    #pragma unroll
    for (int g = 0; g < 4; ++g)
        #pragma unroll
        for (int half = 0; half < 2; ++half)
            o[half] = __builtin_amdgcn_mfma_f32_32x32x16_bf16(pa[g], vb[g][half], o[half], 0, 0, 0);
}

__device__ __forceinline__ void qdisp(bool last, const short8 ak0, const short8 ak1,
                                      const short8 bq, const short8 vb[4][2], int kb,
                                      int hi, int qmin, int qg,
                                      f32x16 o[2], float& lp)
{
    if (!last) {
        qpv<false>(ak0, ak1, bq, vb, kb, hi, qg, o, lp);
    } else if (kb <= qmin + 31) {
        if (kb + 63 <= qmin) qpv<false>(ak0, ak1, bq, vb, kb, hi, qg, o, lp);
        else                 qpv<true >(ak0, ak1, bq, vb, kb, hi, qg, o, lp);
    }
}

__global__ __launch_bounds__(256, 2) void attn_q64(const unsigned short* __restrict__ qh,
                                                   const unsigned short* __restrict__ khm,
                                                   const unsigned short* __restrict__ vt,
                                                   const float* __restrict__ nq,
                                                   const float* __restrict__ nk,
                                                   float* __restrict__ out)
{
    const int L = blockIdx.x;            // 512; L%8 == bh%8 -> XCD-pinned
    const int bh = L & 31;
    const int p  = L >> 5;               // pair {31-p, p}
    const int h = bh & 15, b = bh >> 4;

    const int tid = threadIdx.x, w = tid >> 6, lane = tid & 63;
    const int seg = w >> 1, kh = w & 1;
    const int l31 = lane & 31, hi = lane >> 5;

    const int qt  = seg ? p : 31 - p;
    const int nts = (qt >> 1) + 1;       // this wave's active tiles
    const int nt0 = ((31 - p) >> 1) + 1; // loop trip count (heavy)
    const int qmin0 = qt * 64, qmin1 = qt * 64 + 32;
    const int qg0 = qmin0 + l31, qg1 = qmin1 + l31;

    __shared__ __align__(16) unsigned char smem[33792];

    const unsigned short* qbh = qh  + (size_t)bh * SEQ * 16;
    const unsigned short* kbh = khm + (size_t)bh * SEQ * 16;

    // fold rq (incl. QSCALE) into Q-frags once
    const float rq0 = QSCALE / fmaxf(sqrtf(nq[b * SEQ + qg0]), 1e-6f);
    const float rq1 = QSCALE / fmaxf(sqrtf(nq[b * SEQ + qg1]), 1e-6f);
    const short8 bq0 = fold8(*(const short8*)&qbh[qg0 * 16 + 8 * hi], rq0);
    const short8 bq1 = fold8(*(const short8*)&qbh[qg1 * 16 + 8 * hi], rq1);

    f32x16 o0[2] = {}, o1[2] = {};
    float lp0 = 0.0f, lp1 = 0.0f;

    const unsigned short* kwin = kbh + (64 * kh + l31) * 16 + 8 * hi;
    const float* nkb = nk + b * SEQ + 64 * kh + l31;
    short8 ak0 = *(const short8*)(kwin);
    short8 ak1 = *(const short8*)(kwin + 32 * 16);
    float nk0c = nkb[0];
    float nk1c = nkb[32];

    const int vsub = lane >> 4, vslot = lane & 15;

#define STAGEV(kt_, buf_) do {                                                                    \
        const int k0_ = (kt_) * 128;                                                              \
        _Pragma("unroll")                                                                         \
        for (int i = 0; i < 4; ++i) {                                                             \
            const int c = 4 * w + i;                                                              \
            const int dh = 4 * c + vsub;                                                          \
            const int so = 8 * (vslot ^ (dh & 15));                                               \
            __builtin_amdgcn_global_load_lds(                                                     \
                (GPTR)&vt[((size_t)b * DIM + h * DH + dh) * SEQ + k0_ + so],                      \
                (LPTR)(smem + (buf_) * 16384 + c * 1024), 16, 0, 0);                              \
        }                                                                                         \
    } while (0)

    STAGEV(0, 0);

    #pragma unroll 1
    for (int kt = 0; kt < nt0; ++kt) {
        short8 an0 = ak0, an1 = ak1;
        float nk0n = nk0c, nk1n = nk1c;
        if (kt + 1 < nt0) {
            STAGEV(kt + 1, (kt + 1) & 1);
            an0 = *(const short8*)(kwin + (size_t)(kt + 1) * 128 * 16);
            an1 = *(const short8*)(kwin + (size_t)(kt + 1) * 128 * 16 + 32 * 16);
            nk0n = nkb[(kt + 1) * 128];
            nk1n = nkb[(kt + 1) * 128 + 32];
            asm volatile("s_waitcnt vmcnt(8)" ::: "memory");   // drain tile kt stage only
        } else {
            asm volatile("s_waitcnt vmcnt(0)" ::: "memory");
        }
        __builtin_amdgcn_sched_barrier(0);
        __builtin_amdgcn_s_barrier();        // stage(kt) visible to all waves

        if (kt < nts) {
            const unsigned short* Vs = (const unsigned short*)(smem + (kt & 1) * 16384);
            const int kb = kt * 128 + 64 * kh;

            // fold rk into K-frags (per-lane scalar; arrived >=1 tile ago)
            const float rk0 = 1.0f / fmaxf(sqrtf(nk0c), 1e-6f);
            const float rk1 = 1.0f / fmaxf(sqrtf(nk1c), 1e-6f);
            const short8 af0 = fold8(ak0, rk0);
            const short8 af1 = fold8(ak1, rk1);

            // V fragments: read ONCE, reused for both q-halves
            short8 vb[4][2];
            #pragma unroll
            for (int g = 0; g < 4; ++g)
                #pragma unroll
                for (int half = 0; half < 2; ++half) {
                    const int row = half * 32 + l31;
                    const int slot = (8 * kh + 2 * g + hi) ^ (row & 15);
                    vb[g][half] = *(const short8*)&Vs[row * 128 + 8 * slot];
                }

            const bool last = (kt == nts - 1);
            __builtin_amdgcn_s_setprio(1);
            qdisp(last, af0, af1, bq0, vb, kb, hi, qmin0, qg0, o0, lp0);
            qdisp(last, af0, af1, bq1, vb, kb, hi, qmin1, qg1, o1, lp1);
            __builtin_amdgcn_s_setprio(0);
        }

        ak0 = an0; ak1 = an1;
        nk0c = nk0n; nk1c = nk1n;
        __builtin_amdgcn_s_barrier();        // all waves done reading buf kt
    }
#undef STAGEV

    // ---- epilogue: 2-way kh merge per (seg, q-half), normalize, store ----
    lp0 += __shfl_xor(lp0, 32);
    lp1 += __shfl_xor(lp1, 32);

    __syncthreads();                         // V dbuf dead; reuse smem
    float* Os = (float*)smem;                // [2 seg][64 q][64 lane] = 32 KB
    float* Ls = (float*)(smem + 32768);      // [2 seg][2 qi][64 lane] = 1 KB

    if (kh == 1) {
        #pragma unroll
        for (int half = 0; half < 2; ++half)
            #pragma unroll
            for (int r = 0; r < 16; ++r) {
                const int q = (r & 3) + 8 * (r >> 2) + 4 * hi;
                Os[(seg * 64 + q) * 64 + half * 32 + l31]      = o0[half][r];
                Os[(seg * 64 + 32 + q) * 64 + half * 32 + l31] = o1[half][r];
            }
        Ls[seg * 128 + lane]      = lp0;
        Ls[seg * 128 + 64 + lane] = lp1;
    }
    __syncthreads();
    if (kh == 0) {
        float lt0 = lp0 + Ls[seg * 128 + lane];
        float lt1 = lp1 + Ls[seg * 128 + 64 + lane];
        const float inv0 = 1.0f / fmaxf(lt0, 1e-6f);
        const float inv1 = 1.0f / fmaxf(lt1, 1e-6f);
        #pragma unroll
        for (int r = 0; r < 16; ++r) {
            const int q = (r & 3) + 8 * (r >> 2) + 4 * hi;
            const float iv0 = __shfl(inv0, q);
            const float iv1 = __shfl(inv1, q);
            #pragma unroll
            for (int half = 0; half < 2; ++half) {
                const float v0 = (o0[half][r] + Os[(seg * 64 + q) * 64 + half * 32 + l31]) * iv0;
                const float v1 = (o1[half][r] + Os[(seg * 64 + 32 + q) * 64 + half * 32 + l31]) * iv1;
                __builtin_nontemporal_store(v0,
                    &out[((size_t)b * SEQ + qmin0 + q) * DIM + h * DH + half * 32 + l31]);
                __builtin_nontemporal_store(v1,
                    &out[((size_t)b * SEQ + qmin1 + q) * DIM + h * DH + half * 32 + l31]);
            }
        }
    }
}

extern "C" void kernel_launch(void* const* d_in, const int* in_sizes, int n_in,
                              void* d_out, int out_size, void* d_ws, size_t ws_size,
                              hipStream_t stream)
{
    const float* x   = (const float*)d_in[0];
    // d_in[1] = mask (causal, analytic)
    const float* Wqk = (const float*)d_in[2];
    const float* Wv  = (const float*)d_in[3];
    float* out = (float*)d_out;

    // workspace: xb 8MB | vt 8MB | wcat 3MB | qh 2MB | khm 2MB | norms 32KB (~23MB)
    unsigned short* xb   = (unsigned short*)d_ws;
    unsigned short* vt   = xb   + (size_t)MROWS * DIM;
    unsigned short* wcat = vt   + (size_t)BATCH * DIM * SEQ;
    unsigned short* qh   = wcat + (size_t)1536 * DIM;
    unsigned short* khm  = qh   + (size_t)32 * SEQ * 16;
    float* norms = (float*)(khm + (size_t)32 * SEQ * 16);
    float* nq = norms;
    float* nk = norms + MROWS;

    conv3<<<5640, 256, 0, stream>>>(x, Wqk, Wv, xb, wcat, norms);
    gemm_mfma<<<768, 256, 0, stream>>>(xb, wcat, qh, khm, vt, nq, nk);
    attn_q64<<<512, 256, 0, stream>>>(qh, khm, vt, nq, nk, out);
}